// Round 2
// baseline (965.518 us; speedup 1.0000x reference)
//
#include <hip/hip_runtime.h>
#include <cstddef>

// ---------------- tap geometry (compile-time) ----------------
// merged 17x17 kernel nonzeros: union of
//   even 9x9 grid (dil2 9x9 + dil4 3x3), 5x5 center (dil1), dil5 3x3, dil7 3x3
__host__ __device__ constexpr bool is_tap(int dy, int dx) {
  const bool ev = ((dy & 1) == 0) && ((dx & 1) == 0);
  const bool c5 = (dy >= -2 && dy <= 2 && dx >= -2 && dx <= 2);
  const bool d5 = ((dy == -5 || dy == 0 || dy == 5) && (dx == -5 || dx == 0 || dx == 5));
  const bool d7 = ((dy == -7 || dy == 0 || dy == 7) && (dx == -7 || dx == 0 || dx == 7));
  return ev || c5 || d5 || d7;
}
__host__ __device__ constexpr bool is_extra(int dy, int dx) {
  return is_tap(dy, dx) && !(((dy & 1) == 0) && ((dx & 1) == 0));
}
// slot 0..80: even grid ((dy+8)/2)*9+((dx+8)/2); slot 81..112: extras in scan order
__host__ __device__ constexpr int ext_slot(int dy, int dx) {
  int n = 0;
  for (int yy = -8; yy <= 8; ++yy)
    for (int xx = -8; xx <= 8; ++xx) {
      if (is_extra(yy, xx)) {
        if (yy == dy && xx == dx) return n;
        ++n;
      }
    }
  return -1;
}
__host__ __device__ constexpr int count_extras() {
  int n = 0;
  for (int yy = -8; yy <= 8; ++yy)
    for (int xx = -8; xx <= 8; ++xx) n += is_extra(yy, xx) ? 1 : 0;
  return n;
}
static_assert(count_extras() == 32, "extra tap count");
#define NTAPS 113

__device__ __forceinline__ int tap_slot(int dy, int dx) {
  if (!is_tap(dy, dx)) return -1;
  if (((dy & 1) == 0) && ((dx & 1) == 0))
    return ((dy + 8) >> 1) * 9 + ((dx + 8) >> 1);
  return 81 + ext_slot(dy, dx);
}

// ---------------- prep kernel: synthesize merged 17x17 kernels ----------------
struct BranchP {
  int ksz, scale, CIN, HID, COUT, S, nd;
  int dils[3];
  const float *dw_w, *dw_b, *w1, *b1, *w2, *b2, *dilw;
};

__device__ void run_branch(int tid, const BranchP P,
                           const float* w0, float* merged,
                           float* bufA, float* bufB) {
  const int S = P.S, ksz = P.ksz, CIN = P.CIN, HID = P.HID, COUT = P.COUT;
  const int SS = S * S;
  // 1) pad (bottom/right) + pixel_unshuffle (scale==1 -> copy)
  for (int i = tid; i < CIN * SS; i += 256) {
    const int cc = i / SS, rem = i % SS, hh = rem / S, ww = rem % S;
    const int s2 = P.scale * P.scale;
    const int c = cc / s2, r2 = cc % s2, si = r2 / P.scale, sj = r2 % P.scale;
    const int sh = hh * P.scale + si, sw = ww * P.scale + sj;
    bufA[i] = (sh < 17 && sw < 17) ? w0[c * 289 + sh * 17 + sw] : 0.f;
  }
  __syncthreads();
  // 2) depthwise 3x3, pad 1
  for (int i = tid; i < CIN * SS; i += 256) {
    const int ch = i / SS, rem = i % SS, y = rem / S, x = rem % S;
    float acc = P.dw_b[ch];
    for (int u = 0; u < 3; ++u)
      for (int v = 0; v < 3; ++v) {
        const int yy = y + u - 1, xx = x + v - 1;
        if (yy >= 0 && yy < S && xx >= 0 && xx < S)
          acc += bufA[ch * SS + yy * S + xx] * P.dw_w[ch * 9 + u * 3 + v];
      }
    bufB[i] = acc;
  }
  __syncthreads();
  // 3) 1x1 + bias + relu  (bufB -> bufA)
  for (int i = tid; i < HID * SS; i += 256) {
    const int ho = i / SS, rem = i % SS;
    float acc = P.b1[ho];
    for (int ci = 0; ci < CIN; ++ci) acc += bufB[ci * SS + rem] * P.w1[ho * CIN + ci];
    bufA[i] = fmaxf(acc, 0.f);
  }
  __syncthreads();
  // 4) 1x1 + bias  (bufA -> bufB)
  for (int i = tid; i < COUT * SS; i += 256) {
    const int po = i / SS, rem = i % SS;
    float acc = P.b2[po];
    for (int ci = 0; ci < HID; ++ci) acc += bufA[ci * SS + rem] * P.w2[po * HID + ci];
    bufB[i] = acc;
  }
  __syncthreads();
  // 5) bilinear S -> ksz  (bufB -> bufA)
  for (int i = tid; i < COUT * ksz * ksz; i += 256) {
    const int c = i / (ksz * ksz), rem = i % (ksz * ksz), oy = rem / ksz, ox = rem % ksz;
    const float ratio = (float)S / (float)ksz;
    float sy = fminf(fmaxf((oy + 0.5f) * ratio - 0.5f, 0.f), (float)(S - 1));
    float sx = fminf(fmaxf((ox + 0.5f) * ratio - 0.5f, 0.f), (float)(S - 1));
    const int y0 = (int)sy; const int y1 = min(y0 + 1, S - 1); const float ty = sy - (float)y0;
    const int x0 = (int)sx; const int x1 = min(x0 + 1, S - 1); const float tx = sx - (float)x0;
    const float* img = bufB + c * SS;
    const float top = img[y0 * S + x0] * (1.f - tx) + img[y0 * S + x1] * tx;
    const float bot = img[y1 * S + x0] * (1.f - tx) + img[y1 * S + x1] * tx;
    bufA[i] = top * (1.f - ty) + bot * ty;
  }
  __syncthreads();
  // 6) per-dil channel mix + zero-interleave + accumulate into merged
  for (int di = 0; di < P.nd; ++di) {
    const int d = P.dils[di];
    const int e = d * (ksz - 1) + 1, pp = 8 - e / 2;
    for (int i = tid; i < 3 * ksz * ksz; i += 256) {
      const int p = i / (ksz * ksz), rem = i % (ksz * ksz), ih = rem / ksz, iw = rem % ksz;
      float acc = 0.f;
      for (int c2 = 0; c2 < COUT; ++c2)
        acc += bufA[c2 * ksz * ksz + rem] * P.dilw[(di * 3 + p) * COUT + c2];
      merged[p * 289 + (pp + d * ih) * 17 + (pp + d * iw)] += acc;
    }
  }
  __syncthreads();
}

__global__ __launch_bounds__(256) void prep_kernel(
    const float* __restrict__ A1, const float* __restrict__ B1,
    const float* __restrict__ A2, const float* __restrict__ B2,
    const float* __restrict__ A3, const float* __restrict__ B3,
    const float* __restrict__ dw_w3, const float* __restrict__ dw_b3,
    const float* __restrict__ w1_3, const float* __restrict__ b1_3,
    const float* __restrict__ w2_3, const float* __restrict__ b2_3,
    const float* __restrict__ dilw3,
    const float* __restrict__ dw_w5, const float* __restrict__ dw_b5,
    const float* __restrict__ w1_5, const float* __restrict__ b1_5,
    const float* __restrict__ w2_5, const float* __restrict__ b2_5,
    const float* __restrict__ dilw5,
    const float* __restrict__ dw_w9, const float* __restrict__ dw_b9,
    const float* __restrict__ w1_9, const float* __restrict__ b1_9,
    const float* __restrict__ w2_9, const float* __restrict__ b2_9,
    const float* __restrict__ dilw9,
    float* __restrict__ wk) {
  const int o = blockIdx.x;
  const int tid = threadIdx.x;
  __shared__ float w0[3 * 289];
  __shared__ float merged[3 * 289];
  __shared__ float bufA[3888];
  __shared__ float bufB[3888];

  // weight0[o,c] = A_c[o] (17x4) @ B_c[o] (4x17)
  for (int i = tid; i < 3 * 289; i += 256) {
    const int c = i / 289, rem = i % 289, k = rem / 17, l = rem % 17;
    const float* A = (c == 0 ? A1 : (c == 1 ? A2 : A3)) + o * 68;
    const float* B = (c == 0 ? B1 : (c == 1 ? B2 : B3)) + o * 68;
    float s = 0.f;
    for (int r = 0; r < 4; ++r) s += A[k * 4 + r] * B[r * 17 + l];
    w0[i] = s;
    merged[i] = 0.f;
  }
  __syncthreads();

  {
    BranchP P{3, 4, 48, 64, 12, 5, 3, {4, 5, 7}, dw_w3, dw_b3, w1_3, b1_3, w2_3, b2_3, dilw3};
    run_branch(tid, P, w0, merged, bufA, bufB);
  }
  {
    BranchP P{5, 2, 12, 48, 6, 9, 1, {1, 0, 0}, dw_w5, dw_b5, w1_5, b1_5, w2_5, b2_5, dilw5};
    run_branch(tid, P, w0, merged, bufA, bufB);
  }
  {
    BranchP P{9, 1, 3, 12, 3, 17, 1, {2, 0, 0}, dw_w9, dw_b9, w1_9, b1_9, w2_9, b2_9, dilw9};
    run_branch(tid, P, w0, merged, bufA, bufB);
  }

  // pack tap weights: wk[o][slot][p], p<3, slot-pad to 4 floats
  for (int i = tid; i < 289; i += 256) {
    const int dy = i / 17 - 8, dx = i % 17 - 8;
    const int slot = tap_slot(dy, dx);
    if (slot >= 0) {
      float* dst = wk + ((size_t)o * NTAPS + slot) * 4;
      dst[0] = merged[0 * 289 + i];
      dst[1] = merged[1 * 289 + i];
      dst[2] = merged[2 * 289 + i];
      dst[3] = 0.f;
    }
  }
}

// ---------------- main conv kernel ----------------
// out[n][c*3+p][y][x] = sum_taps merged[c][p][dy][dx] * x[n][c][y+dy][x+dx]
// block: (yt, c, n); 256 threads = 32 tx * 8 ty; thread: 2 rows x 8 cols x 3 p
//
// LDS tile is XOR-swizzled at 16B granularity: float-index bits [4:2] ^= bits [7:5].
// All LDS accesses are 16B-aligned float4, so a granule stays contiguous; the
// swizzle makes the 32B-lane-stride window reads bank-uniform (was 2x conflict).
#define XTS(i) ((i) ^ ((((i) >> 5) & 7) << 2))

__global__ __launch_bounds__(256, 4) void conv17_kernel(
    const float* __restrict__ xin, const float* __restrict__ wk,
    float* __restrict__ out) {
  const int yt = blockIdx.x;   // 0..15 (16-row stripes)
  const int ch = blockIdx.y;   // 0..63
  const int n  = blockIdx.z;   // 0..7
  const int tid = threadIdx.x;

  __shared__ __align__(128) float xt[32 * 272];  // rows y0-8..y0+23, cols -8..263

  const float* xim = xin + ((size_t)(n * 64 + ch)) * 65536;
  // block-uniform weight pointer -> scalar (s_load) weight reads
  const float4* __restrict__ wkv = (const float4*)wk + (size_t)ch * NTAPS;
  const int y0 = yt * 16;

  // load input tile (float4; cols c4 in [2,65] are fully interior, rest are pad-zero)
  for (int i = tid; i < 32 * 68; i += 256) {
    const int r = i / 68, c4 = i % 68;
    const int gy = y0 - 8 + r;
    float4 v = make_float4(0.f, 0.f, 0.f, 0.f);
    if (gy >= 0 && gy < 256 && c4 >= 2 && c4 <= 65)
      v = *(const float4*)(xim + gy * 256 + (c4 * 4 - 8));
    *(float4*)&xt[XTS(r * 272 + c4 * 4)] = v;
  }
  __syncthreads();

  const int tx = tid & 31, ty = tid >> 5;
  const int x0 = tx * 8;
  const int r0 = ty * 2;  // local out-row base

  float acc[2][3][8] __attribute__((aligned(16))) = {};

  // ---- part A: even 9x9 grid (81 taps), weights shared across both rows ----
  #pragma unroll 1
  for (int a = 0; a < 9; ++a) {          // dy = 2a-8
    float4 w[9];
    #pragma unroll
    for (int b = 0; b < 9; ++b) w[b] = wkv[a * 9 + b];
    #pragma unroll
    for (int rr = 0; rr < 2; ++rr) {
      const int rbase = (r0 + rr + 2 * a) * 272 + x0;
      float win[24];
      #pragma unroll
      for (int j = 0; j < 6; ++j) *(float4*)&win[4 * j] = *(const float4*)&xt[XTS(rbase + 4 * j)];
      #pragma unroll
      for (int b = 0; b < 9; ++b) {      // dx = 2b-8
        #pragma unroll
        for (int j = 0; j < 8; ++j) {
          const float xv = win[2 * b + j];
          acc[rr][0][j] = fmaf(w[b].x, xv, acc[rr][0][j]);
          acc[rr][1][j] = fmaf(w[b].y, xv, acc[rr][1][j]);
          acc[rr][2][j] = fmaf(w[b].z, xv, acc[rr][2][j]);
        }
      }
    }
  }

  // ---- part B: 32 extra taps on rows {-7,-5,-2,-1,0,1,2,5,7} ----
  const int EXROWS[9] = {-7, -5, -2, -1, 0, 1, 2, 5, 7};
  #pragma unroll
  for (int er = 0; er < 9; ++er) {
    const int dy = EXROWS[er];
    #pragma unroll
    for (int rr = 0; rr < 2; ++rr) {
      const int rbase = (r0 + rr + dy + 8) * 272 + x0;
      float win[24];
      #pragma unroll
      for (int j = 0; j < 6; ++j) *(float4*)&win[4 * j] = *(const float4*)&xt[XTS(rbase + 4 * j)];
      #pragma unroll
      for (int dx = -8; dx <= 8; ++dx) {
        if (is_extra(dy, dx)) {          // compile-time constant after unroll
          const int slot = 81 + ext_slot(dy, dx);
          const float4 w = wkv[slot];
          #pragma unroll
          for (int j = 0; j < 8; ++j) {
            const float xv = win[8 + dx + j];
            acc[rr][0][j] = fmaf(w.x, xv, acc[rr][0][j]);
            acc[rr][1][j] = fmaf(w.y, xv, acc[rr][1][j]);
            acc[rr][2][j] = fmaf(w.z, xv, acc[rr][2][j]);
          }
        }
      }
    }
  }

  // ---- store ----
  #pragma unroll
  for (int rr = 0; rr < 2; ++rr) {
    const int gy = y0 + r0 + rr;
    #pragma unroll
    for (int p = 0; p < 3; ++p) {
      float* op = out + (((size_t)n * 192 + ch * 3 + p) * 256 + gy) * 256 + x0;
      *(float4*)(op)     = make_float4(acc[rr][p][0], acc[rr][p][1], acc[rr][p][2], acc[rr][p][3]);
      *(float4*)(op + 4) = make_float4(acc[rr][p][4], acc[rr][p][5], acc[rr][p][6], acc[rr][p][7]);
    }
  }
}

// ---------------- launch ----------------
extern "C" void kernel_launch(void* const* d_in, const int* in_sizes, int n_in,
                              void* d_out, int out_size, void* d_ws, size_t ws_size,
                              hipStream_t stream) {
  const float* xin = (const float*)d_in[0];
  const float* A1 = (const float*)d_in[1];
  const float* B1 = (const float*)d_in[2];
  const float* A2 = (const float*)d_in[3];
  const float* B2 = (const float*)d_in[4];
  const float* A3 = (const float*)d_in[5];
  const float* B3 = (const float*)d_in[6];
  const float* dw_w3 = (const float*)d_in[7];
  const float* dw_b3 = (const float*)d_in[8];
  const float* w1_3 = (const float*)d_in[9];
  const float* b1_3 = (const float*)d_in[10];
  const float* w2_3 = (const float*)d_in[11];
  const float* b2_3 = (const float*)d_in[12];
  const float* dilw3 = (const float*)d_in[13];
  const float* dw_w5 = (const float*)d_in[14];
  const float* dw_b5 = (const float*)d_in[15];
  const float* w1_5 = (const float*)d_in[16];
  const float* b1_5 = (const float*)d_in[17];
  const float* w2_5 = (const float*)d_in[18];
  const float* b2_5 = (const float*)d_in[19];
  const float* dilw5 = (const float*)d_in[20];
  const float* dw_w9 = (const float*)d_in[21];
  const float* dw_b9 = (const float*)d_in[22];
  const float* w1_9 = (const float*)d_in[23];
  const float* b1_9 = (const float*)d_in[24];
  const float* w2_9 = (const float*)d_in[25];
  const float* b2_9 = (const float*)d_in[26];
  const float* dilw9 = (const float*)d_in[27];

  float* wk = (float*)d_ws;  // 64 * 113 * 4 floats = 115,712 B

  prep_kernel<<<64, 256, 0, stream>>>(
      A1, B1, A2, B2, A3, B3,
      dw_w3, dw_b3, w1_3, b1_3, w2_3, b2_3, dilw3,
      dw_w5, dw_b5, w1_5, b1_5, w2_5, b2_5, dilw5,
      dw_w9, dw_b9, w1_9, b1_9, w2_9, b2_9, dilw9,
      wk);

  dim3 grid(16, 64, 8);
  conv17_kernel<<<grid, 256, 0, stream>>>(xin, wk, (float*)d_out);
}

// Round 3
// 351.864 us; speedup vs baseline: 2.7440x; 2.7440x over previous
//
#include <hip/hip_runtime.h>
#include <cstddef>

// ---------------- tap geometry (compile-time) ----------------
// merged 17x17 kernel nonzeros: union of
//   even 9x9 grid (dil2 9x9 + dil4 3x3), 5x5 center (dil1), dil5 3x3, dil7 3x3
__host__ __device__ constexpr bool is_tap(int dy, int dx) {
  const bool ev = ((dy & 1) == 0) && ((dx & 1) == 0);
  const bool c5 = (dy >= -2 && dy <= 2 && dx >= -2 && dx <= 2);
  const bool d5 = ((dy == -5 || dy == 0 || dy == 5) && (dx == -5 || dx == 0 || dx == 5));
  const bool d7 = ((dy == -7 || dy == 0 || dy == 7) && (dx == -7 || dx == 0 || dx == 7));
  return ev || c5 || d5 || d7;
}
__host__ __device__ constexpr bool is_extra(int dy, int dx) {
  return is_tap(dy, dx) && !(((dy & 1) == 0) && ((dx & 1) == 0));
}
// slot 0..80: even grid ((dy+8)/2)*9+((dx+8)/2); slot 81..112: extras in scan order
__host__ __device__ constexpr int ext_slot(int dy, int dx) {
  int n = 0;
  for (int yy = -8; yy <= 8; ++yy)
    for (int xx = -8; xx <= 8; ++xx) {
      if (is_extra(yy, xx)) {
        if (yy == dy && xx == dx) return n;
        ++n;
      }
    }
  return -1;
}
__host__ __device__ constexpr int count_extras() {
  int n = 0;
  for (int yy = -8; yy <= 8; ++yy)
    for (int xx = -8; xx <= 8; ++xx) n += is_extra(yy, xx) ? 1 : 0;
  return n;
}
static_assert(count_extras() == 32, "extra tap count");
#define NTAPS 113

__device__ __forceinline__ int tap_slot(int dy, int dx) {
  if (!is_tap(dy, dx)) return -1;
  if (((dy & 1) == 0) && ((dx & 1) == 0))
    return ((dy + 8) >> 1) * 9 + ((dx + 8) >> 1);
  return 81 + ext_slot(dy, dx);
}

// ---------------- prep kernel: synthesize merged 17x17 kernels ----------------
struct BranchP {
  int ksz, scale, CIN, HID, COUT, S, nd;
  int dils[3];
  const float *dw_w, *dw_b, *w1, *b1, *w2, *b2, *dilw;
};

__device__ void run_branch(int tid, const BranchP P,
                           const float* w0, float* merged,
                           float* bufA, float* bufB) {
  const int S = P.S, ksz = P.ksz, CIN = P.CIN, HID = P.HID, COUT = P.COUT;
  const int SS = S * S;
  // 1) pad (bottom/right) + pixel_unshuffle (scale==1 -> copy)
  for (int i = tid; i < CIN * SS; i += 256) {
    const int cc = i / SS, rem = i % SS, hh = rem / S, ww = rem % S;
    const int s2 = P.scale * P.scale;
    const int c = cc / s2, r2 = cc % s2, si = r2 / P.scale, sj = r2 % P.scale;
    const int sh = hh * P.scale + si, sw = ww * P.scale + sj;
    bufA[i] = (sh < 17 && sw < 17) ? w0[c * 289 + sh * 17 + sw] : 0.f;
  }
  __syncthreads();
  // 2) depthwise 3x3, pad 1
  for (int i = tid; i < CIN * SS; i += 256) {
    const int ch = i / SS, rem = i % SS, y = rem / S, x = rem % S;
    float acc = P.dw_b[ch];
    for (int u = 0; u < 3; ++u)
      for (int v = 0; v < 3; ++v) {
        const int yy = y + u - 1, xx = x + v - 1;
        if (yy >= 0 && yy < S && xx >= 0 && xx < S)
          acc += bufA[ch * SS + yy * S + xx] * P.dw_w[ch * 9 + u * 3 + v];
      }
    bufB[i] = acc;
  }
  __syncthreads();
  // 3) 1x1 + bias + relu  (bufB -> bufA)
  for (int i = tid; i < HID * SS; i += 256) {
    const int ho = i / SS, rem = i % SS;
    float acc = P.b1[ho];
    for (int ci = 0; ci < CIN; ++ci) acc += bufB[ci * SS + rem] * P.w1[ho * CIN + ci];
    bufA[i] = fmaxf(acc, 0.f);
  }
  __syncthreads();
  // 4) 1x1 + bias  (bufA -> bufB)
  for (int i = tid; i < COUT * SS; i += 256) {
    const int po = i / SS, rem = i % SS;
    float acc = P.b2[po];
    for (int ci = 0; ci < HID; ++ci) acc += bufA[ci * SS + rem] * P.w2[po * HID + ci];
    bufB[i] = acc;
  }
  __syncthreads();
  // 5) bilinear S -> ksz  (bufB -> bufA)
  for (int i = tid; i < COUT * ksz * ksz; i += 256) {
    const int c = i / (ksz * ksz), rem = i % (ksz * ksz), oy = rem / ksz, ox = rem % ksz;
    const float ratio = (float)S / (float)ksz;
    float sy = fminf(fmaxf((oy + 0.5f) * ratio - 0.5f, 0.f), (float)(S - 1));
    float sx = fminf(fmaxf((ox + 0.5f) * ratio - 0.5f, 0.f), (float)(S - 1));
    const int y0 = (int)sy; const int y1 = min(y0 + 1, S - 1); const float ty = sy - (float)y0;
    const int x0 = (int)sx; const int x1 = min(x0 + 1, S - 1); const float tx = sx - (float)x0;
    const float* img = bufB + c * SS;
    const float top = img[y0 * S + x0] * (1.f - tx) + img[y0 * S + x1] * tx;
    const float bot = img[y1 * S + x0] * (1.f - tx) + img[y1 * S + x1] * tx;
    bufA[i] = top * (1.f - ty) + bot * ty;
  }
  __syncthreads();
  // 6) per-dil channel mix + zero-interleave + accumulate into merged
  for (int di = 0; di < P.nd; ++di) {
    const int d = P.dils[di];
    const int e = d * (ksz - 1) + 1, pp = 8 - e / 2;
    for (int i = tid; i < 3 * ksz * ksz; i += 256) {
      const int p = i / (ksz * ksz), rem = i % (ksz * ksz), ih = rem / ksz, iw = rem % ksz;
      float acc = 0.f;
      for (int c2 = 0; c2 < COUT; ++c2)
        acc += bufA[c2 * ksz * ksz + rem] * P.dilw[(di * 3 + p) * COUT + c2];
      merged[p * 289 + (pp + d * ih) * 17 + (pp + d * iw)] += acc;
    }
  }
  __syncthreads();
}

__global__ __launch_bounds__(256) void prep_kernel(
    const float* __restrict__ A1, const float* __restrict__ B1,
    const float* __restrict__ A2, const float* __restrict__ B2,
    const float* __restrict__ A3, const float* __restrict__ B3,
    const float* __restrict__ dw_w3, const float* __restrict__ dw_b3,
    const float* __restrict__ w1_3, const float* __restrict__ b1_3,
    const float* __restrict__ w2_3, const float* __restrict__ b2_3,
    const float* __restrict__ dilw3,
    const float* __restrict__ dw_w5, const float* __restrict__ dw_b5,
    const float* __restrict__ w1_5, const float* __restrict__ b1_5,
    const float* __restrict__ w2_5, const float* __restrict__ b2_5,
    const float* __restrict__ dilw5,
    const float* __restrict__ dw_w9, const float* __restrict__ dw_b9,
    const float* __restrict__ w1_9, const float* __restrict__ b1_9,
    const float* __restrict__ w2_9, const float* __restrict__ b2_9,
    const float* __restrict__ dilw9,
    float* __restrict__ wk) {
  const int o = blockIdx.x;
  const int tid = threadIdx.x;
  __shared__ float w0[3 * 289];
  __shared__ float merged[3 * 289];
  __shared__ float bufA[3888];
  __shared__ float bufB[3888];

  // weight0[o,c] = A_c[o] (17x4) @ B_c[o] (4x17)
  for (int i = tid; i < 3 * 289; i += 256) {
    const int c = i / 289, rem = i % 289, k = rem / 17, l = rem % 17;
    const float* A = (c == 0 ? A1 : (c == 1 ? A2 : A3)) + o * 68;
    const float* B = (c == 0 ? B1 : (c == 1 ? B2 : B3)) + o * 68;
    float s = 0.f;
    for (int r = 0; r < 4; ++r) s += A[k * 4 + r] * B[r * 17 + l];
    w0[i] = s;
    merged[i] = 0.f;
  }
  __syncthreads();

  {
    BranchP P{3, 4, 48, 64, 12, 5, 3, {4, 5, 7}, dw_w3, dw_b3, w1_3, b1_3, w2_3, b2_3, dilw3};
    run_branch(tid, P, w0, merged, bufA, bufB);
  }
  {
    BranchP P{5, 2, 12, 48, 6, 9, 1, {1, 0, 0}, dw_w5, dw_b5, w1_5, b1_5, w2_5, b2_5, dilw5};
    run_branch(tid, P, w0, merged, bufA, bufB);
  }
  {
    BranchP P{9, 1, 3, 12, 3, 17, 1, {2, 0, 0}, dw_w9, dw_b9, w1_9, b1_9, w2_9, b2_9, dilw9};
    run_branch(tid, P, w0, merged, bufA, bufB);
  }

  // pack tap weights: wk[o][slot][p], p<3, slot-pad to 4 floats
  for (int i = tid; i < 289; i += 256) {
    const int dy = i / 17 - 8, dx = i % 17 - 8;
    const int slot = tap_slot(dy, dx);
    if (slot >= 0) {
      float* dst = wk + ((size_t)o * NTAPS + slot) * 4;
      dst[0] = merged[0 * 289 + i];
      dst[1] = merged[1 * 289 + i];
      dst[2] = merged[2 * 289 + i];
      dst[3] = 0.f;
    }
  }
}

// ---------------- main conv kernel ----------------
// out[n][c*3+p][y][x] = sum_taps merged[c][p][dy][dx] * x[n][c][y+dy][x+dx]
// block: (yt, c, n); 256 threads = 16 tx * 16 ty; thread: 1 row x 16 cols x 3 p
//
// LDS tile XOR-swizzled at 16B granularity: float-index bits [4:2] ^= bits [7:5].
// With 64B lane stride (16 cols/thread), 16 tx lanes land exactly 2-per-16B-unit
// -> conflict-free (2-way aliasing is free on CDNA4).
#define XTS(i) ((i) ^ ((((i) >> 5) & 7) << 2))

__global__ __launch_bounds__(256) void conv17_kernel(
    const float* __restrict__ xin, const float* __restrict__ wk,
    float* __restrict__ out) {
  const int yt = blockIdx.x;   // 0..15 (16-row stripes)
  const int ch = blockIdx.y;   // 0..63
  const int n  = blockIdx.z;   // 0..7
  const int tid = threadIdx.x;

  __shared__ __align__(128) float xt[32 * 272];  // rows y0-8..y0+23, cols -8..263

  const float* xim = xin + ((size_t)(n * 64 + ch)) * 65536;
  // block-uniform weight pointer -> scalar (s_load) weight reads (SGPR operands)
  const float4* __restrict__ wkv = (const float4*)wk + (size_t)ch * NTAPS;
  const int y0 = yt * 16;

  // load input tile (float4; cols c4 in [2,65] are fully interior, rest are pad-zero)
  for (int i = tid; i < 32 * 68; i += 256) {
    const int r = i / 68, c4 = i % 68;
    const int gy = y0 - 8 + r;
    float4 v = make_float4(0.f, 0.f, 0.f, 0.f);
    if (gy >= 0 && gy < 256 && c4 >= 2 && c4 <= 65)
      v = *(const float4*)(xim + gy * 256 + (c4 * 4 - 8));
    *(float4*)&xt[XTS(r * 272 + c4 * 4)] = v;
  }
  __syncthreads();

  const int tx = tid & 15, ty = tid >> 4;
  const int x0 = tx * 16;        // output cols [x0, x0+16)

  float acc[3][16] __attribute__((aligned(16))) = {};

  // ---- part A: even 9x9 grid (81 taps) ----
  #pragma unroll 1
  for (int a = 0; a < 9; ++a) {          // dy = 2a-8; tile row = ty + 2a
    const int rbase = (ty + 2 * a) * 272 + x0;
    float win[32];
    #pragma unroll
    for (int j = 0; j < 8; ++j) *(float4*)&win[4 * j] = *(const float4*)&xt[XTS(rbase + 4 * j)];
    #pragma unroll
    for (int b = 0; b < 9; ++b) {        // dx = 2b-8
      const float4 w = wkv[a * 9 + b];
      #pragma unroll
      for (int j = 0; j < 16; ++j) {
        const float xv = win[2 * b + j];
        acc[0][j] = fmaf(w.x, xv, acc[0][j]);
        acc[1][j] = fmaf(w.y, xv, acc[1][j]);
        acc[2][j] = fmaf(w.z, xv, acc[2][j]);
      }
    }
  }

  // ---- part B: 32 extra taps on rows dy in {-7,-5,-2,-1,0,1,2,5,7} ----
  const int EXROWS[9] = {-7, -5, -2, -1, 0, 1, 2, 5, 7};
  #pragma unroll
  for (int er = 0; er < 9; ++er) {
    const int dy = EXROWS[er];           // compile-time after unroll
    const int rbase = (ty + dy + 8) * 272 + x0;
    float win[32];
    #pragma unroll
    for (int j = 0; j < 8; ++j) *(float4*)&win[4 * j] = *(const float4*)&xt[XTS(rbase + 4 * j)];
    #pragma unroll
    for (int dx = -8; dx <= 8; ++dx) {
      if (is_extra(dy, dx)) {            // compile-time constant after unroll
        const int slot = 81 + ext_slot(dy, dx);
        const float4 w = wkv[slot];
        #pragma unroll
        for (int j = 0; j < 16; ++j) {
          const float xv = win[8 + dx + j];
          acc[0][j] = fmaf(w.x, xv, acc[0][j]);
          acc[1][j] = fmaf(w.y, xv, acc[1][j]);
          acc[2][j] = fmaf(w.z, xv, acc[2][j]);
        }
      }
    }
  }

  // ---- store ----
  const int gy = y0 + ty;
  #pragma unroll
  for (int p = 0; p < 3; ++p) {
    float* op = out + (((size_t)n * 192 + ch * 3 + p) * 256 + gy) * 256 + x0;
    #pragma unroll
    for (int q = 0; q < 4; ++q)
      *(float4*)(op + 4 * q) = make_float4(acc[p][4 * q + 0], acc[p][4 * q + 1],
                                           acc[p][4 * q + 2], acc[p][4 * q + 3]);
  }
}

// ---------------- launch ----------------
extern "C" void kernel_launch(void* const* d_in, const int* in_sizes, int n_in,
                              void* d_out, int out_size, void* d_ws, size_t ws_size,
                              hipStream_t stream) {
  const float* xin = (const float*)d_in[0];
  const float* A1 = (const float*)d_in[1];
  const float* B1 = (const float*)d_in[2];
  const float* A2 = (const float*)d_in[3];
  const float* B2 = (const float*)d_in[4];
  const float* A3 = (const float*)d_in[5];
  const float* B3 = (const float*)d_in[6];
  const float* dw_w3 = (const float*)d_in[7];
  const float* dw_b3 = (const float*)d_in[8];
  const float* w1_3 = (const float*)d_in[9];
  const float* b1_3 = (const float*)d_in[10];
  const float* w2_3 = (const float*)d_in[11];
  const float* b2_3 = (const float*)d_in[12];
  const float* dilw3 = (const float*)d_in[13];
  const float* dw_w5 = (const float*)d_in[14];
  const float* dw_b5 = (const float*)d_in[15];
  const float* w1_5 = (const float*)d_in[16];
  const float* b1_5 = (const float*)d_in[17];
  const float* w2_5 = (const float*)d_in[18];
  const float* b2_5 = (const float*)d_in[19];
  const float* dilw5 = (const float*)d_in[20];
  const float* dw_w9 = (const float*)d_in[21];
  const float* dw_b9 = (const float*)d_in[22];
  const float* w1_9 = (const float*)d_in[23];
  const float* b1_9 = (const float*)d_in[24];
  const float* w2_9 = (const float*)d_in[25];
  const float* b2_9 = (const float*)d_in[26];
  const float* dilw9 = (const float*)d_in[27];

  float* wk = (float*)d_ws;  // 64 * 113 * 4 floats = 115,712 B

  prep_kernel<<<64, 256, 0, stream>>>(
      A1, B1, A2, B2, A3, B3,
      dw_w3, dw_b3, w1_3, b1_3, w2_3, b2_3, dilw3,
      dw_w5, dw_b5, w1_5, b1_5, w2_5, b2_5, dilw5,
      dw_w9, dw_b9, w1_9, b1_9, w2_9, b2_9, dilw9,
      wk);

  dim3 grid(16, 64, 8);
  conv17_kernel<<<grid, 256, 0, stream>>>(xin, wk, (float*)d_out);
}

// Round 4
// 345.457 us; speedup vs baseline: 2.7949x; 1.0185x over previous
//
#include <hip/hip_runtime.h>
#include <cstddef>

typedef float v2f __attribute__((ext_vector_type(2)));

// ---------------- tap geometry (compile-time) ----------------
// merged 17x17 kernel nonzeros: union of
//   even 9x9 grid (dil2 9x9 + dil4 3x3), 5x5 center (dil1), dil5 3x3, dil7 3x3
__host__ __device__ constexpr bool is_tap(int dy, int dx) {
  const bool ev = ((dy & 1) == 0) && ((dx & 1) == 0);
  const bool c5 = (dy >= -2 && dy <= 2 && dx >= -2 && dx <= 2);
  const bool d5 = ((dy == -5 || dy == 0 || dy == 5) && (dx == -5 || dx == 0 || dx == 5));
  const bool d7 = ((dy == -7 || dy == 0 || dy == 7) && (dx == -7 || dx == 0 || dx == 7));
  return ev || c5 || d5 || d7;
}
__host__ __device__ constexpr bool is_extra(int dy, int dx) {
  return is_tap(dy, dx) && !(((dy & 1) == 0) && ((dx & 1) == 0));
}
// slot 0..80: even grid ((dy+8)/2)*9+((dx+8)/2); slot 81..112: extras in scan order
__host__ __device__ constexpr int ext_slot(int dy, int dx) {
  int n = 0;
  for (int yy = -8; yy <= 8; ++yy)
    for (int xx = -8; xx <= 8; ++xx) {
      if (is_extra(yy, xx)) {
        if (yy == dy && xx == dx) return n;
        ++n;
      }
    }
  return -1;
}
__host__ __device__ constexpr int count_extras() {
  int n = 0;
  for (int yy = -8; yy <= 8; ++yy)
    for (int xx = -8; xx <= 8; ++xx) n += is_extra(yy, xx) ? 1 : 0;
  return n;
}
static_assert(count_extras() == 32, "extra tap count");
#define NTAPS 113

__device__ __forceinline__ int tap_slot(int dy, int dx) {
  if (!is_tap(dy, dx)) return -1;
  if (((dy & 1) == 0) && ((dx & 1) == 0))
    return ((dy + 8) >> 1) * 9 + ((dx + 8) >> 1);
  return 81 + ext_slot(dy, dx);
}

// ---------------- prep kernel: synthesize merged 17x17 kernels ----------------
struct BranchP {
  int ksz, scale, CIN, HID, COUT, S, nd;
  int dils[3];
  const float *dw_w, *dw_b, *w1, *b1, *w2, *b2, *dilw;
};

__device__ void run_branch(int tid, const BranchP P,
                           const float* w0, float* merged,
                           float* bufA, float* bufB) {
  const int S = P.S, ksz = P.ksz, CIN = P.CIN, HID = P.HID, COUT = P.COUT;
  const int SS = S * S;
  // 1) pad (bottom/right) + pixel_unshuffle (scale==1 -> copy)
  for (int i = tid; i < CIN * SS; i += 256) {
    const int cc = i / SS, rem = i % SS, hh = rem / S, ww = rem % S;
    const int s2 = P.scale * P.scale;
    const int c = cc / s2, r2 = cc % s2, si = r2 / P.scale, sj = r2 % P.scale;
    const int sh = hh * P.scale + si, sw = ww * P.scale + sj;
    bufA[i] = (sh < 17 && sw < 17) ? w0[c * 289 + sh * 17 + sw] : 0.f;
  }
  __syncthreads();
  // 2) depthwise 3x3, pad 1
  for (int i = tid; i < CIN * SS; i += 256) {
    const int ch = i / SS, rem = i % SS, y = rem / S, x = rem % S;
    float acc = P.dw_b[ch];
    for (int u = 0; u < 3; ++u)
      for (int v = 0; v < 3; ++v) {
        const int yy = y + u - 1, xx = x + v - 1;
        if (yy >= 0 && yy < S && xx >= 0 && xx < S)
          acc += bufA[ch * SS + yy * S + xx] * P.dw_w[ch * 9 + u * 3 + v];
      }
    bufB[i] = acc;
  }
  __syncthreads();
  // 3) 1x1 + bias + relu  (bufB -> bufA)
  for (int i = tid; i < HID * SS; i += 256) {
    const int ho = i / SS, rem = i % SS;
    float acc = P.b1[ho];
    for (int ci = 0; ci < CIN; ++ci) acc += bufB[ci * SS + rem] * P.w1[ho * CIN + ci];
    bufA[i] = fmaxf(acc, 0.f);
  }
  __syncthreads();
  // 4) 1x1 + bias  (bufA -> bufB)
  for (int i = tid; i < COUT * SS; i += 256) {
    const int po = i / SS, rem = i % SS;
    float acc = P.b2[po];
    for (int ci = 0; ci < HID; ++ci) acc += bufA[ci * SS + rem] * P.w2[po * HID + ci];
    bufB[i] = acc;
  }
  __syncthreads();
  // 5) bilinear S -> ksz  (bufB -> bufA)
  for (int i = tid; i < COUT * ksz * ksz; i += 256) {
    const int c = i / (ksz * ksz), rem = i % (ksz * ksz), oy = rem / ksz, ox = rem % ksz;
    const float ratio = (float)S / (float)ksz;
    float sy = fminf(fmaxf((oy + 0.5f) * ratio - 0.5f, 0.f), (float)(S - 1));
    float sx = fminf(fmaxf((ox + 0.5f) * ratio - 0.5f, 0.f), (float)(S - 1));
    const int y0 = (int)sy; const int y1 = min(y0 + 1, S - 1); const float ty = sy - (float)y0;
    const int x0 = (int)sx; const int x1 = min(x0 + 1, S - 1); const float tx = sx - (float)x0;
    const float* img = bufB + c * SS;
    const float top = img[y0 * S + x0] * (1.f - tx) + img[y0 * S + x1] * tx;
    const float bot = img[y1 * S + x0] * (1.f - tx) + img[y1 * S + x1] * tx;
    bufA[i] = top * (1.f - ty) + bot * ty;
  }
  __syncthreads();
  // 6) per-dil channel mix + zero-interleave + accumulate into merged
  for (int di = 0; di < P.nd; ++di) {
    const int d = P.dils[di];
    const int e = d * (ksz - 1) + 1, pp = 8 - e / 2;
    for (int i = tid; i < 3 * ksz * ksz; i += 256) {
      const int p = i / (ksz * ksz), rem = i % (ksz * ksz), ih = rem / ksz, iw = rem % ksz;
      float acc = 0.f;
      for (int c2 = 0; c2 < COUT; ++c2)
        acc += bufA[c2 * ksz * ksz + rem] * P.dilw[(di * 3 + p) * COUT + c2];
      merged[p * 289 + (pp + d * ih) * 17 + (pp + d * iw)] += acc;
    }
  }
  __syncthreads();
}

__global__ __launch_bounds__(256) void prep_kernel(
    const float* __restrict__ A1, const float* __restrict__ B1,
    const float* __restrict__ A2, const float* __restrict__ B2,
    const float* __restrict__ A3, const float* __restrict__ B3,
    const float* __restrict__ dw_w3, const float* __restrict__ dw_b3,
    const float* __restrict__ w1_3, const float* __restrict__ b1_3,
    const float* __restrict__ w2_3, const float* __restrict__ b2_3,
    const float* __restrict__ dilw3,
    const float* __restrict__ dw_w5, const float* __restrict__ dw_b5,
    const float* __restrict__ w1_5, const float* __restrict__ b1_5,
    const float* __restrict__ w2_5, const float* __restrict__ b2_5,
    const float* __restrict__ dilw5,
    const float* __restrict__ dw_w9, const float* __restrict__ dw_b9,
    const float* __restrict__ w1_9, const float* __restrict__ b1_9,
    const float* __restrict__ w2_9, const float* __restrict__ b2_9,
    const float* __restrict__ dilw9,
    float* __restrict__ wk) {
  const int o = blockIdx.x;
  const int tid = threadIdx.x;
  __shared__ float w0[3 * 289];
  __shared__ float merged[3 * 289];
  __shared__ float bufA[3888];
  __shared__ float bufB[3888];

  // weight0[o,c] = A_c[o] (17x4) @ B_c[o] (4x17)
  for (int i = tid; i < 3 * 289; i += 256) {
    const int c = i / 289, rem = i % 289, k = rem / 17, l = rem % 17;
    const float* A = (c == 0 ? A1 : (c == 1 ? A2 : A3)) + o * 68;
    const float* B = (c == 0 ? B1 : (c == 1 ? B2 : B3)) + o * 68;
    float s = 0.f;
    for (int r = 0; r < 4; ++r) s += A[k * 4 + r] * B[r * 17 + l];
    w0[i] = s;
    merged[i] = 0.f;
  }
  __syncthreads();

  {
    BranchP P{3, 4, 48, 64, 12, 5, 3, {4, 5, 7}, dw_w3, dw_b3, w1_3, b1_3, w2_3, b2_3, dilw3};
    run_branch(tid, P, w0, merged, bufA, bufB);
  }
  {
    BranchP P{5, 2, 12, 48, 6, 9, 1, {1, 0, 0}, dw_w5, dw_b5, w1_5, b1_5, w2_5, b2_5, dilw5};
    run_branch(tid, P, w0, merged, bufA, bufB);
  }
  {
    BranchP P{9, 1, 3, 12, 3, 17, 1, {2, 0, 0}, dw_w9, dw_b9, w1_9, b1_9, w2_9, b2_9, dilw9};
    run_branch(tid, P, w0, merged, bufA, bufB);
  }

  // pack tap weights: wk[o][slot][p], p<3, slot-pad to 4 floats
  for (int i = tid; i < 289; i += 256) {
    const int dy = i / 17 - 8, dx = i % 17 - 8;
    const int slot = tap_slot(dy, dx);
    if (slot >= 0) {
      float* dst = wk + ((size_t)o * NTAPS + slot) * 4;
      dst[0] = merged[0 * 289 + i];
      dst[1] = merged[1 * 289 + i];
      dst[2] = merged[2 * 289 + i];
      dst[3] = 0.f;
    }
  }
}

// ---------------- main conv kernel ----------------
// out[n][c*3+p][y][x] = sum_taps merged[c][p][dy][dx] * x[n][c][y+dy][x+dx]
// block: (yt, c, n); 256 threads = 16 tx * 16 ty; thread: 1 row x 16 cols x 3 p
//
// LDS tile XOR-swizzled at 16B granularity: float-index bits [4:2] ^= bits [7:5].
// Verified by enumeration: within each 16-lane quarter (64B lane stride), the
// 16 lanes land exactly 2-per-16B-unit -> conflict-free-equivalent.
//
// Unified 15-window pass (tap rows dy in {-8..8} \ {-3,3}); even-grid taps use
// packed dual-FP32 FMA (v_pk_fma_f32 via <2 x float> llvm.fma); extras scalar.
#define XTS(i) ((i) ^ ((((i) >> 5) & 7) << 2))

__global__ __launch_bounds__(256) void conv17_kernel(
    const float* __restrict__ xin, const float* __restrict__ wk,
    float* __restrict__ out) {
  const int yt = blockIdx.x;   // 0..15 (16-row stripes)
  const int ch = blockIdx.y;   // 0..63
  const int n  = blockIdx.z;   // 0..7
  const int tid = threadIdx.x;

  __shared__ __align__(128) float xt[32 * 272];  // rows y0-8..y0+23, cols -8..263

  const float* xim = xin + ((size_t)(n * 64 + ch)) * 65536;
  // block-uniform weight pointer -> scalar (s_load) weight reads (SGPR operands)
  const float4* __restrict__ wkv = (const float4*)wk + (size_t)ch * NTAPS;
  const int y0 = yt * 16;

  // load input tile (float4; cols c4 in [2,65] are fully interior, rest are pad-zero)
  for (int i = tid; i < 32 * 68; i += 256) {
    const int r = i / 68, c4 = i % 68;
    const int gy = y0 - 8 + r;
    float4 v = make_float4(0.f, 0.f, 0.f, 0.f);
    if (gy >= 0 && gy < 256 && c4 >= 2 && c4 <= 65)
      v = *(const float4*)(xim + gy * 256 + (c4 * 4 - 8));
    *(float4*)&xt[XTS(r * 272 + c4 * 4)] = v;
  }
  __syncthreads();

  const int tx = tid & 15, ty = tid >> 4;
  const int x0 = tx * 16;        // output cols [x0, x0+16)

  v2f acc2[3][8];                // acc2[p][m] = outputs (2m, 2m+1)
  #pragma unroll
  for (int p = 0; p < 3; ++p)
    #pragma unroll
    for (int m = 0; m < 8; ++m) acc2[p][m] = (v2f)0.f;

  // ---- 6 "simple" even rows (9 even taps only, no extras): dy = -8,-6,-4,4,6,8 ----
  const int SIMPLE_A[6] = {0, 1, 2, 6, 7, 8};   // a = (dy+8)/2
  #pragma unroll 1
  for (int ii = 0; ii < 6; ++ii) {
    const int a = SIMPLE_A[ii];
    const int rbase = (ty + 2 * a) * 272 + x0;
    v2f win2[16] __attribute__((aligned(16)));
    #pragma unroll
    for (int q = 0; q < 8; ++q)
      *(float4*)&win2[2 * q] = *(const float4*)&xt[XTS(rbase + 4 * q)];
    #pragma unroll
    for (int b = 0; b < 9; ++b) {
      const float4 w = wkv[a * 9 + b];
      const v2f w0s = w.x, w1s = w.y, w2s = w.z;
      #pragma unroll
      for (int m = 0; m < 8; ++m) {
        const v2f xv = win2[b + m];          // = (win[2b+2m], win[2b+2m+1])
        acc2[0][m] = __builtin_elementwise_fma(w0s, xv, acc2[0][m]);
        acc2[1][m] = __builtin_elementwise_fma(w1s, xv, acc2[1][m]);
        acc2[2][m] = __builtin_elementwise_fma(w2s, xv, acc2[2][m]);
      }
    }
  }

  // ---- 9 "mixed" rows: dy in {-7,-5,-2,-1,0,1,2,5,7} ----
  const int MROWS[9] = {-7, -5, -2, -1, 0, 1, 2, 5, 7};
  #pragma unroll
  for (int er = 0; er < 9; ++er) {
    const int d = MROWS[er];                 // compile-time after unroll
    const int rbase = (ty + d + 8) * 272 + x0;
    v2f win2[16] __attribute__((aligned(16)));
    #pragma unroll
    for (int q = 0; q < 8; ++q)
      *(float4*)&win2[2 * q] = *(const float4*)&xt[XTS(rbase + 4 * q)];
    // even-grid taps on this row (d even): packed
    if ((d & 1) == 0) {
      const int a = (d + 8) >> 1;
      #pragma unroll
      for (int b = 0; b < 9; ++b) {
        const float4 w = wkv[a * 9 + b];
        const v2f w0s = w.x, w1s = w.y, w2s = w.z;
        #pragma unroll
        for (int m = 0; m < 8; ++m) {
          const v2f xv = win2[b + m];
          acc2[0][m] = __builtin_elementwise_fma(w0s, xv, acc2[0][m]);
          acc2[1][m] = __builtin_elementwise_fma(w1s, xv, acc2[1][m]);
          acc2[2][m] = __builtin_elementwise_fma(w2s, xv, acc2[2][m]);
        }
      }
    }
    // extra (odd-position) taps on this row: scalar
    #pragma unroll
    for (int dx = -8; dx <= 8; ++dx) {
      if (is_extra(d, dx)) {                 // compile-time constant after unroll
        const int slot = 81 + ext_slot(d, dx);
        const float4 w = wkv[slot];
        #pragma unroll
        for (int j = 0; j < 16; ++j) {
          const int k = 8 + dx + j;          // window float index
          const float xv = win2[k >> 1][k & 1];
          acc2[0][j >> 1][j & 1] = fmaf(w.x, xv, acc2[0][j >> 1][j & 1]);
          acc2[1][j >> 1][j & 1] = fmaf(w.y, xv, acc2[1][j >> 1][j & 1]);
          acc2[2][j >> 1][j & 1] = fmaf(w.z, xv, acc2[2][j >> 1][j & 1]);
        }
      }
    }
  }

  // ---- store ----
  const int gy = y0 + ty;
  #pragma unroll
  for (int p = 0; p < 3; ++p) {
    float* op = out + (((size_t)n * 192 + ch * 3 + p) * 256 + gy) * 256 + x0;
    #pragma unroll
    for (int q = 0; q < 4; ++q)
      *(float4*)(op + 4 * q) = make_float4(acc2[p][2 * q][0], acc2[p][2 * q][1],
                                           acc2[p][2 * q + 1][0], acc2[p][2 * q + 1][1]);
  }
}

// ---------------- launch ----------------
extern "C" void kernel_launch(void* const* d_in, const int* in_sizes, int n_in,
                              void* d_out, int out_size, void* d_ws, size_t ws_size,
                              hipStream_t stream) {
  const float* xin = (const float*)d_in[0];
  const float* A1 = (const float*)d_in[1];
  const float* B1 = (const float*)d_in[2];
  const float* A2 = (const float*)d_in[3];
  const float* B2 = (const float*)d_in[4];
  const float* A3 = (const float*)d_in[5];
  const float* B3 = (const float*)d_in[6];
  const float* dw_w3 = (const float*)d_in[7];
  const float* dw_b3 = (const float*)d_in[8];
  const float* w1_3 = (const float*)d_in[9];
  const float* b1_3 = (const float*)d_in[10];
  const float* w2_3 = (const float*)d_in[11];
  const float* b2_3 = (const float*)d_in[12];
  const float* dilw3 = (const float*)d_in[13];
  const float* dw_w5 = (const float*)d_in[14];
  const float* dw_b5 = (const float*)d_in[15];
  const float* w1_5 = (const float*)d_in[16];
  const float* b1_5 = (const float*)d_in[17];
  const float* w2_5 = (const float*)d_in[18];
  const float* b2_5 = (const float*)d_in[19];
  const float* dilw5 = (const float*)d_in[20];
  const float* dw_w9 = (const float*)d_in[21];
  const float* dw_b9 = (const float*)d_in[22];
  const float* w1_9 = (const float*)d_in[23];
  const float* b1_9 = (const float*)d_in[24];
  const float* w2_9 = (const float*)d_in[25];
  const float* b2_9 = (const float*)d_in[26];
  const float* dilw9 = (const float*)d_in[27];

  float* wk = (float*)d_ws;  // 64 * 113 * 4 floats = 115,712 B

  prep_kernel<<<64, 256, 0, stream>>>(
      A1, B1, A2, B2, A3, B3,
      dw_w3, dw_b3, w1_3, b1_3, w2_3, b2_3, dilw3,
      dw_w5, dw_b5, w1_5, b1_5, w2_5, b2_5, dilw5,
      dw_w9, dw_b9, w1_9, b1_9, w2_9, b2_9, dilw9,
      wk);

  dim3 grid(16, 64, 8);
  conv17_kernel<<<grid, 256, 0, stream>>>(xin, wk, (float*)d_out);
}